// Round 17
// baseline (117.695 us; speedup 1.0000x reference)
//
#include <hip/hip_runtime.h>
#include <stdint.h>

#define S_LEN 2048
#define NBATCH 2
#define DMODEL 1024
#define NHEAD 16
#define HDIM 64
#define MROWS (NBATCH * S_LEN)   // 4096
#define LOG2E 1.44269504f

typedef __bf16 bf16x8 __attribute__((ext_vector_type(8)));
typedef float f32x4 __attribute__((ext_vector_type(4)));
typedef float f32x16 __attribute__((ext_vector_type(16)));
typedef uint32_t u32x4 __attribute__((ext_vector_type(4)));

__device__ __forceinline__ f32x4 mfma_bf16(bf16x8 a, bf16x8 b, f32x4 c) {
    return __builtin_amdgcn_mfma_f32_16x16x32_bf16(a, b, c, 0, 0, 0);
}
__device__ __forceinline__ f32x16 mfma32(bf16x8 a, bf16x8 b, f32x16 c) {
    return __builtin_amdgcn_mfma_f32_32x32x16_bf16(a, b, c, 0, 0, 0);
}

__device__ __forceinline__ ushort f2bf(float f) {
    __bf16 h = (__bf16)f;
    return __builtin_bit_cast(ushort, h);
}

// pack two f32 -> one u32 of 2x bf16 (low = lo, high = hi). No builtin on gfx950 (m240).
__device__ __forceinline__ uint32_t cvtpk(float lo, float hi) {
    uint32_t r;
    asm("v_cvt_pk_bf16_f32 %0, %1, %2" : "=v"(r) : "v"(lo), "v"(hi));
    return r;
}
// swap: a' = {lanes<32: a, lanes>=32: b(from low half)}, b' = {lanes<32: a(from high half), >=32: b}
__device__ __forceinline__ void pl32swap(uint32_t& a, uint32_t& b) {
    auto r = __builtin_amdgcn_permlane32_swap(a, b, false, false);
    a = r[0];
    b = r[1];
}
// cross-half (lane ^ 32) max via permlane32_swap -- pure VALU, no ds_bpermute round-trip.
__device__ __forceinline__ float xhalf_max(float x) {
    uint32_t u = __builtin_bit_cast(uint32_t, x);
    auto r = __builtin_amdgcn_permlane32_swap(u, u, false, false);
    return fmaxf(__builtin_bit_cast(float, r[0]), __builtin_bit_cast(float, r[1]));
}
__device__ __forceinline__ float fexp2(float x) { return __builtin_amdgcn_exp2f(x); }

#define MAX3(a, b, c) fmaxf(fmaxf((a), (b)), (c))   // clang fuses to v_max3_f32 (T17)

#define GLOAD_LDS16(gp, lp)                                                             \
    __builtin_amdgcn_global_load_lds((const uint32_t __attribute__((address_space(1)))*)(gp), \
                                     (uint32_t __attribute__((address_space(3)))*)(lp), 16, 0, 0)

// ---------------- fused fp32 -> bf16 cast for all 5 inputs (1 launch) ----------------
// blocks [0,4096): x (1M float4). [4096,5120): Wq (*qscale). [5120,6144): Wk.
// [6144,7168): Wv. [7168,8192): Wo. All regions exact multiples of 256 threads.
// NOTE: workspace footprint stays within 48MB (R9 lesson); mask math stays f32-exact
// in the attn loop (R11 lesson); no register-hoists across attn MFMA blocks (R13 lesson:
// VGPR ceiling -> scratch spill, 634MB/dispatch).
__global__ void cast_all_kernel(const float* __restrict__ x,  const float* __restrict__ Wq,
                                const float* __restrict__ Wk, const float* __restrict__ Wv,
                                const float* __restrict__ Wo,
                                ushort* __restrict__ xb, ushort* __restrict__ wqkv,
                                ushort* __restrict__ wob, float qscale) {
    const int blk = blockIdx.x;
    const float* src;
    ushort* dst;
    float scale = 1.0f;
    int base;
    if (blk < 4096)      { src = x;  dst = xb;                         base = blk; }
    else if (blk < 5120) { src = Wq; dst = wqkv;                       base = blk - 4096; scale = qscale; }
    else if (blk < 6144) { src = Wk; dst = wqkv + DMODEL * DMODEL;     base = blk - 5120; }
    else if (blk < 7168) { src = Wv; dst = wqkv + 2 * DMODEL * DMODEL; base = blk - 6144; }
    else                 { src = Wo; dst = wob;                        base = blk - 7168; }
    const int i = base * blockDim.x + threadIdx.x;
    float4 v = reinterpret_cast<const float4*>(src)[i];
    ushort4 o;
    o.x = f2bf(v.x * scale);
    o.y = f2bf(v.y * scale);
    o.z = f2bf(v.z * scale);
    o.w = f2bf(v.w * scale);
    reinterpret_cast<ushort4*>(dst)[i] = o;
}

// ---------------- bf16 GEMM, C = A * B^T  (A[M,K], B[N,K]) ----------------
// Natural block mapping (bx fastest; swizzles regressed -- do not swizzle).
// BN=128/NSUB=2 for gemm<0> (32KB staging, 3 blocks/CU); BN=64/NSUB=4 for gemm<1>
// (48KB, 2 blocks/CU; R10+R15 wins). NSUB divides the vmcnt(0)+barrier drain events.
// Coalesced epilogues via LDS transpose over the dead staging buffer (R16 win, +4.2us
// on gemm<0>; R17 extends to gemm<1>):
//   EPI==0 (bf16): T[128][136] XOR-swizzled, 8x fully-coalesced 16B stores/thread.
//   EPI==1 (f32):  Tf[128][64] row-rotation swizzle (c+4r)&63 -- any store instr's four
//                  g-row groups land on bank ranges offset by 16 (<=2-way, free per m136);
//                  readback float4 stays 16B-aligned; 8x coalesced float4 stores/thread.
template <int EPI, int BN, int NSUB>
__global__ __launch_bounds__(256, 2) void gemm_bt(
    const ushort* __restrict__ A, const ushort* __restrict__ Bw, const int K,
    ushort* __restrict__ dq, ushort* __restrict__ dk, ushort* __restrict__ dv,
    float* __restrict__ dout)
{
    constexpr int NF = BN / 32;                       // N-fragments per wave (4 or 2)
    constexpr int STAGE = NSUB * (128 + BN) * 32;     // staging ushorts
    constexpr int TP = 136;                           // padded bf16 transpose row
    constexpr int NEED = (EPI == 0) ? 128 * TP : 128 * 64 * 2;  // ushorts for epilogue
    constexpr int SM_SZ = (STAGE < NEED) ? NEED : STAGE;
    __shared__ __align__(16) ushort SMEM[SM_SZ];

    const int tid  = threadIdx.x;
    const int lane = tid & 63;
    const int w    = tid >> 6;
    const int wr   = (w >> 1) * 64;
    const int wc   = (w & 1) * (16 * NF);
    const int g    = lane >> 4;
    const int lr   = lane & 15;
    const int bm   = blockIdx.x * 128;
    const int bn   = blockIdx.y * BN;

    const int srowA  = w * 32 + (lane >> 2);
    const int srowB  = w * (BN / 4) + (lane >> 2);
    const int schunk = (lane & 3) * 8;

    const ushort* gA = A  + (size_t)(bm + srowA) * K + schunk;
    const ushort* gB = Bw + (size_t)(bn + srowB) * K + schunk;

    f32x4 acc[4][NF];
#pragma unroll
    for (int mf = 0; mf < 4; ++mf)
#pragma unroll
        for (int nf = 0; nf < NF; ++nf)
            acc[mf][nf] = (f32x4){0.f, 0.f, 0.f, 0.f};

    for (int kt = 0; kt < K; kt += 32 * NSUB) {
#pragma unroll
        for (int s = 0; s < NSUB; ++s) {
            ushort* As = &SMEM[s * 128 * 32];
            ushort* Bs = &SMEM[NSUB * 128 * 32 + s * BN * 32];
            GLOAD_LDS16(gA + kt + 32 * s, As + (w * 32) * 32);
            GLOAD_LDS16(gA + (size_t)16 * K + kt + 32 * s, As + (w * 32 + 16) * 32);
            GLOAD_LDS16(gB + kt + 32 * s, Bs + (w * (BN / 4)) * 32);
            if constexpr (BN == 128)
                GLOAD_LDS16(gB + (size_t)16 * K + kt + 32 * s, Bs + (w * (BN / 4) + 16) * 32);
        }
        __syncthreads();

#pragma unroll
        for (int hk = 0; hk < NSUB; ++hk) {
            const ushort* As = &SMEM[hk * 128 * 32];
            const ushort* Bs = &SMEM[NSUB * 128 * 32 + hk * BN * 32];
            bf16x8 af[4], bfv[NF];
#pragma unroll
            for (int mf = 0; mf < 4; ++mf)
                af[mf] = *(const bf16x8*)&As[(wr + mf * 16 + lr) * 32 + g * 8];
#pragma unroll
            for (int nf = 0; nf < NF; ++nf)
                bfv[nf] = *(const bf16x8*)&Bs[(wc + nf * 16 + lr) * 32 + g * 8];
#pragma unroll
            for (int mf = 0; mf < 4; ++mf)
#pragma unroll
                for (int nf = 0; nf < NF; ++nf)
                    acc[mf][nf] = mfma_bf16(af[mf], bfv[nf], acc[mf][nf]);
        }
        __syncthreads();
    }

    if constexpr (EPI == 0) {
        // ---- coalesced epilogue: bf16 LDS transpose pass over the dead staging buffer ----
        const int mat = bn >> 10;   // block is mat-pure (128 | 1024)
        ushort* T = SMEM;           // logical T[r][c], addr = r*TP + (c ^ ((r&7)*8))
        if (mat < 2) {
            // Q/K: T[gm][gn] (output rows = gm, contiguous dd = gn)
#pragma unroll
            for (int mf = 0; mf < 4; ++mf)
#pragma unroll
                for (int nf = 0; nf < NF; ++nf)
#pragma unroll
                    for (int i = 0; i < 4; ++i) {
                        const int r = wr + mf * 16 + 4 * g + i;
                        const int c = wc + nf * 16 + lr;
                        T[r * TP + (c ^ ((r & 7) * 8))] = f2bf(acc[mf][nf][i]);
                    }
        } else {
            // V: T[gn][gm] (output rows = gn-derived vrow, contiguous ss = gm)
#pragma unroll
            for (int mf = 0; mf < 4; ++mf)
#pragma unroll
                for (int nf = 0; nf < NF; ++nf)
#pragma unroll
                    for (int i = 0; i < 4; ++i) {
                        const int r = wc + nf * 16 + lr;
                        const int c = wr + mf * 16 + 4 * g + i;
                        T[r * TP + (c ^ ((r & 7) * 8))] = f2bf(acc[mf][nf][i]);
                    }
        }
        __syncthreads();
        // readback: 2048 16B-chunks / 256 threads = 8 each, fully coalesced stores
#pragma unroll
        for (int cc = 0; cc < 8; ++cc) {
            const int ch = tid + cc * 256;
            const int r  = ch >> 4;            // row 0..127
            const int e0 = (ch & 15) * 8;      // element offset (8-aligned)
            const bf16x8 v = *(const bf16x8*)&T[r * TP + (e0 ^ ((r & 7) * 8))];
            if (mat < 2) {
                const int gm  = bm + r;
                const int bb  = gm >> 11;
                const int ss  = gm & 2047;
                const int gnp = bn + e0;
                const int hh  = (gnp & 1023) >> 6;
                const int dd0 = gnp & 63;
                ushort* dst = (mat == 0 ? dq : dk) +
                              ((size_t)(bb * NHEAD + hh) * S_LEN + ss) * HDIM + dd0;
                *(bf16x8*)dst = v;
            } else {
                const int rr  = (bn & 1023) + r;
                const int hh  = rr >> 6;
                const int dd  = rr & 63;
                const int gm0 = bm + e0;
                const int bb  = gm0 >> 11;
                const int ss0 = gm0 & 2047;
                ushort* dst = dv + ((size_t)(bb * NHEAD + hh) * HDIM + dd) * S_LEN + ss0;
                *(bf16x8*)dst = v;
            }
        }
    } else {
        // ---- coalesced f32 epilogue (R17): Tf[128][64] with row-rotation swizzle ----
        float* Tf = reinterpret_cast<float*>(SMEM);   // elem addr = r*64 + ((c + 4r) & 63)
#pragma unroll
        for (int mf = 0; mf < 4; ++mf)
#pragma unroll
            for (int nf = 0; nf < NF; ++nf)
#pragma unroll
                for (int i = 0; i < 4; ++i) {
                    const int r = wr + mf * 16 + 4 * g + i;
                    const int c = wc + nf * 16 + lr;
                    Tf[r * 64 + ((c + 4 * r) & 63)] = acc[mf][nf][i];
                }
        __syncthreads();
        // readback: 2048 float4-chunks / 256 threads = 8 each, fully coalesced stores
#pragma unroll
        for (int cc = 0; cc < 8; ++cc) {
            const int ch = tid + cc * 256;
            const int r  = ch >> 4;            // row 0..127
            const int e0 = (ch & 15) * 4;      // f32 offset (4-aligned)
            const float4 v = *(const float4*)&Tf[r * 64 + ((e0 + 4 * r) & 63)];
            *(float4*)&dout[(size_t)(bm + r) * DMODEL + bn + e0] = v;
        }
    }
}

// ---------------- flash attention v10 (verified R5/R7/R10, FROZEN): KV-split + in-reg P + ones-MFMA l ----------------
// grid (B*H, S/128), 512 threads = 8 waves. Waves 0-3: kv [0,1024); waves 4-7: kv [1024,2048),
// same 4x32 q-rows; partials merged through LDS at the end. Wave supply 4096 (16 waves/CU --
// structural cap: every split variant either blows LDS or needs a >=64MB global merge).
// P in-register (cvtpk+permlane32_swap); l via ones-A MFMA on the idle matrix pipe;
// cross-half max via permlane; max3 tree; K/V double-buffered; 1 barrier/tile.
// DO NOT: hoist load-arrays across MFMA blocks (R13: scratch blowup), remove staging
// (R12: 2.15x), fold mask through bf16 (R11), per-ks interleave (R3), XCD-swizzle (R8).
__global__ __launch_bounds__(512, 4) void attn_kernel(
    const ushort* __restrict__ Qp,   // [B*H][S][64]  (pre-scaled by log2e/32)
    const ushort* __restrict__ Kp,   // [B*H][S][64]
    const ushort* __restrict__ Vp,   // [B*H][64][S]  (transposed)
    const float*  __restrict__ mask, // [B][S]
    ushort* __restrict__ Y)          // [B*S][DMODEL]
{
    __shared__ __align__(16) ushort Ks[2][2][64 * 64]; // [grp][buf][kv][hd] chunk-swizzled
    __shared__ __align__(16) ushort Vs[2][2][64 * 64]; // [grp][buf][d][kv]  chunk-swizzled

    const int tid  = threadIdx.x;
    const int lane = tid & 63;
    const int w    = tid >> 6;       // 0..7
    const int qsub = w & 3;          // q sub-block within the 128-row block
    const int grp  = w >> 2;         // kv half: 0 -> [0,S/2), 1 -> [S/2,S)
    const int q    = lane & 31;      // lane's q-col / row index in 32-row frags
    const int hsel = lane >> 5;      // half-wave
    const int l7   = lane & 7;
    const int bh   = blockIdx.x;     // head-major grid
    const int b    = bh >> 4;
    const int h    = bh & 15;
    const int q0   = blockIdx.y * 128 + qsub * 32;

    const ushort* Qh = Qp + (size_t)bh * S_LEN * HDIM;
    const ushort* Kh = Kp + (size_t)bh * S_LEN * HDIM;
    const ushort* Vh = Vp + (size_t)bh * HDIM * S_LEN;
    const float*  mb = mask + (size_t)b * S_LEN;

    // Q fragments (B-operand): lane holds q-row q0+q, k-slice ks: hd = ks*16 + hsel*8 + 0..7
    bf16x8 qf[4];
#pragma unroll
    for (int ks = 0; ks < 4; ++ks)
        qf[ks] = *(const bf16x8*)&Qh[(size_t)(q0 + q) * HDIM + ks * 16 + hsel * 8];

    // ones A-fragment for the l-row MFMA
    const __bf16 oneb = (__bf16)1.0f;
    const bf16x8 onesf = {oneb, oneb, oneb, oneb, oneb, oneb, oneb, oneb};

    // staging: wave stages rows [qsub*8, qsub*8+8) and [+32) of its group's K and V^T tile.
    // gload_lds dest linear; global source pre-swizzled chunk = c8 ^ (row&7) (rule 21)
    const int srow = qsub * 8 + (lane >> 3);
    const int swz  = ((lane & 7) ^ ((lane >> 3) & 7)) * 8;
    const ushort* gK = Kh + (size_t)srow * HDIM + swz;
    const ushort* gV = Vh + (size_t)srow * S_LEN + swz;
    const int lK0 = (qsub * 8) * 64, lK1 = (qsub * 8 + 32) * 64;

    f32x16 acc0 = {}, acc1 = {}, lacc = {};
    float mrun = -__builtin_inff();

    const int kvbase = grp * (S_LEN / 2);
    const int NT = (S_LEN / 2) / 64;

    // prologue: stage tile 0 into buf 0
    GLOAD_LDS16(gK + (size_t)kvbase * HDIM, &Ks[grp][0][lK0]);
    GLOAD_LDS16(gK + (size_t)(kvbase + 32) * HDIM, &Ks[grp][0][lK1]);
    GLOAD_LDS16(gV + kvbase, &Vs[grp][0][lK0]);
    GLOAD_LDS16(gV + (size_t)32 * S_LEN + kvbase, &Vs[grp][0][lK1]);
    __syncthreads();

    int buf = 0;
    for (int t = 0; t < NT; ++t) {
        const int kv0 = kvbase + t * 64;
        if (t + 1 < NT) {   // prefetch next tile into other buffer (latency hides under compute)
            GLOAD_LDS16(gK + (size_t)(kv0 + 64) * HDIM, &Ks[grp][buf ^ 1][lK0]);
            GLOAD_LDS16(gK + (size_t)(kv0 + 96) * HDIM, &Ks[grp][buf ^ 1][lK1]);
            GLOAD_LDS16(gV + (kv0 + 64), &Vs[grp][buf ^ 1][lK0]);
            GLOAD_LDS16(gV + (size_t)32 * S_LEN + (kv0 + 64), &Vs[grp][buf ^ 1][lK1]);
        }

        // ---- S^T = K * Q^T : lane owns q-col q; kv rows per verified C/D map ----
        f32x16 sv0 = {}, sv1 = {};
        __builtin_amdgcn_s_setprio(1);
#pragma unroll
        for (int ks = 0; ks < 4; ++ks) {
            const int c = ((ks * 2 + hsel) ^ l7) * 8;
            const bf16x8 kf0 = *(const bf16x8*)&Ks[grp][buf][q * 64 + c];
            const bf16x8 kf1 = *(const bf16x8*)&Ks[grp][buf][(32 + q) * 64 + c];
            sv0 = mfma32(kf0, qf[ks], sv0);
            sv1 = mfma32(kf1, qf[ks], sv1);
        }
        __builtin_amdgcn_s_setprio(0);

        // ---- mask add (log2 units) ----
        // lane reg r holds kv = (r&3) + 8*(r>>2) + 4*hsel (+32 for sv1)
#pragma unroll
        for (int rq = 0; rq < 4; ++rq) {
            const float4 m0 = *(const float4*)&mb[kv0 + rq * 8 + 4 * hsel];
            const float4 m1 = *(const float4*)&mb[kv0 + 32 + rq * 8 + 4 * hsel];
            sv0[4 * rq + 0] = fmaf(m0.x, LOG2E, sv0[4 * rq + 0]);
            sv0[4 * rq + 1] = fmaf(m0.y, LOG2E, sv0[4 * rq + 1]);
            sv0[4 * rq + 2] = fmaf(m0.z, LOG2E, sv0[4 * rq + 2]);
            sv0[4 * rq + 3] = fmaf(m0.w, LOG2E, sv0[4 * rq + 3]);
            sv1[4 * rq + 0] = fmaf(m1.x, LOG2E, sv1[4 * rq + 0]);
            sv1[4 * rq + 1] = fmaf(m1.y, LOG2E, sv1[4 * rq + 1]);
            sv1[4 * rq + 2] = fmaf(m1.z, LOG2E, sv1[4 * rq + 2]);
            sv1[4 * rq + 3] = fmaf(m1.w, LOG2E, sv1[4 * rq + 3]);
        }

        // ---- per-lane max: max3 tree (17 ops), then cross-half via permlane ----
        {
            const float a0 = MAX3(sv0[0], sv0[1], sv0[2]);
            const float a1 = MAX3(sv0[3], sv0[4], sv0[5]);
            const float a2 = MAX3(sv0[6], sv0[7], sv0[8]);
            const float a3 = MAX3(sv0[9], sv0[10], sv0[11]);
            const float a4 = MAX3(sv0[12], sv0[13], sv0[14]);
            const float b0 = MAX3(sv1[0], sv1[1], sv1[2]);
            const float b1 = MAX3(sv1[3], sv1[4], sv1[5]);
            const float b2 = MAX3(sv1[6], sv1[7], sv1[8]);
            const float b3 = MAX3(sv1[9], sv1[10], sv1[11]);
            const float b4 = MAX3(sv1[12], sv1[13], sv1[14]);
            const float c0 = MAX3(sv0[15], a0, a1);
            const float c1 = MAX3(a2, a3, a4);
            const float c2 = MAX3(sv1[15], b0, b1);
            const float c3 = MAX3(b2, b3, b4);
            float pm = fmaxf(fmaxf(c0, c1), fmaxf(c2, c3));
            pm = xhalf_max(pm);   // both halves of a q-col agree (permlane, no LDS)

            // ---- defer-max (T13, THR=8 log2 units) ----
            if (__ballot(pm > mrun + 8.0f) != 0ull) {
                const float mn  = fmaxf(mrun, pm);
                const float fac = fexp2(mrun - mn);
                mrun = mn;
#pragma unroll
                for (int r = 0; r < 16; ++r) {
                    acc0[r] *= fac; acc1[r] *= fac; lacc[r] *= fac;
                }
            }
        }

        // ---- P = exp2(S - m) (32 independent exps; l comes from the ones-MFMA) ----
#pragma unroll
        for (int r = 0; r < 16; ++r) {
            sv0[r] = fexp2(sv0[r] - mrun);
            sv1[r] = fexp2(sv1[r] - mrun);
        }

        // ---- P -> PV B-fragments fully in-register (T12): cvt_pk pairs + permlane32_swap ----
        uint32_t pw[16];
#pragma unroll
        for (int i = 0; i < 8; ++i) pw[i]     = cvtpk(sv0[2 * i], sv0[2 * i + 1]);
#pragma unroll
        for (int i = 0; i < 8; ++i) pw[8 + i] = cvtpk(sv1[2 * i], sv1[2 * i + 1]);
#pragma unroll
        for (int g = 0; g < 4; ++g) {
            pl32swap(pw[g * 4 + 0], pw[g * 4 + 2]);
            pl32swap(pw[g * 4 + 1], pw[g * 4 + 3]);
        }

        // ---- O^T += V^T * P ; l-row += ones * P (idle matrix pipe) ----
        __builtin_amdgcn_s_setprio(1);
#pragma unroll
        for (int ks = 0; ks < 4; ++ks) {
            const int c = ((ks * 2 + hsel) ^ l7) * 8;
            const u32x4 pu = {pw[ks * 4 + 0], pw[ks * 4 + 1], pw[ks * 4 + 2], pw[ks * 4 + 3]};
            const bf16x8 pb  = __builtin_bit_cast(bf16x8, pu);
            const bf16x8 vf0 = *(const bf16x8*)&Vs[grp][buf][q * 64 + c];
            const bf16x8 vf1 = *(const bf16x8*)&Vs[grp][buf][(32 + q) * 64 + c];
            acc0 = mfma32(vf0, pb, acc0);
            acc1 = mfma32(vf1, pb, acc1);
            lacc = mfma32(onesf, pb, lacc);
        }
        __builtin_amdgcn_s_setprio(0);

        __syncthreads();   // drains prefetch vmcnt + all LDS reads of buf
        buf ^= 1;
    }

    const float lrun = lacc[0];   // every row of lacc = sum_k P[k][q]; reg 0 valid for all lanes

    // ---- merge the two kv-half partials through LDS (overlaid on dead K/V buffers) ----
    // xch: [qsub][r(32)][lane(64)] f32 = 32KB over Ks; mlx: [qsub][2][lane] f32 over Vs.
    float* xch = reinterpret_cast<float*>(&Ks[0][0][0]);
    float* mlx = reinterpret_cast<float*>(&Vs[0][0][0]);
    if (grp == 1) {
#pragma unroll
        for (int r = 0; r < 16; ++r) {
            xch[(qsub * 32 + r) * 64 + lane]      = acc0[r];
            xch[(qsub * 32 + 16 + r) * 64 + lane] = acc1[r];
        }
        mlx[(qsub * 2 + 0) * 64 + lane] = mrun;
        mlx[(qsub * 2 + 1) * 64 + lane] = lrun;
    }
    __syncthreads();
    if (grp == 0) {
        const float m2 = mlx[(qsub * 2 + 0) * 64 + lane];
        const float l2 = mlx[(qsub * 2 + 1) * 64 + lane];
        const float mN = fmaxf(mrun, m2);
        const float f1 = fexp2(mrun - mN);
        const float f2 = fexp2(m2 - mN);
        const float inv = 1.0f / (lrun * f1 + l2 * f2);
        const float* src = &xch[(qsub * 32) * 64 + lane];

        // epilogue: O^T -> Y[b*S+q][h*64+d], d = (r&3)+8*(r>>2)+4*hsel (+32 acc1)
        ushort* Yr = Y + (size_t)(b * S_LEN + q0 + q) * DMODEL + h * HDIM;
#pragma unroll
        for (int rq = 0; rq < 4; ++rq) {
            ushort4 o0, o1;
            float v0[4], v1[4];
#pragma unroll
            for (int j = 0; j < 4; ++j) {
                v0[j] = (acc0[4 * rq + j] * f1 + src[(4 * rq + j) * 64] * f2) * inv;
                v1[j] = (acc1[4 * rq + j] * f1 + src[(16 + 4 * rq + j) * 64] * f2) * inv;
            }
            o0.x = f2bf(v0[0]); o0.y = f2bf(v0[1]); o0.z = f2bf(v0[2]); o0.w = f2bf(v0[3]);
            o1.x = f2bf(v1[0]); o1.y = f2bf(v1[1]); o1.z = f2bf(v1[2]); o1.w = f2bf(v1[3]);
            *(ushort4*)&Yr[rq * 8 + 4 * hsel]      = o0;
            *(ushort4*)&Yr[32 + rq * 8 + 4 * hsel] = o1;
        }
    }
}

// ---------------- launch ----------------
extern "C" void kernel_launch(void* const* d_in, const int* in_sizes, int n_in,
                              void* d_out, int out_size, void* d_ws, size_t ws_size,
                              hipStream_t stream)
{
    (void)in_sizes; (void)n_in; (void)out_size; (void)ws_size;
    const float* x  = (const float*)d_in[0];
    const float* am = (const float*)d_in[1];
    const float* Wq = (const float*)d_in[2];
    const float* Wk = (const float*)d_in[3];
    const float* Wv = (const float*)d_in[4];
    const float* Wo = (const float*)d_in[5];
    float* out = (float*)d_out;

    const size_t NX = (size_t)MROWS * DMODEL;   // 4M elems
    const size_t NW = (size_t)DMODEL * DMODEL;  // 1M elems

    ushort* xb   = (ushort*)d_ws;     // x bf16
    ushort* wqkv = xb + NX;           // stacked Wq|Wk|Wv bf16
    ushort* wob  = wqkv + 3 * NW;     // Wo bf16
    ushort* qb   = wob + NW;          // Q  [B,H,S,64] (pre-scaled by log2e/32)
    ushort* kb   = qb + NX;           // K  [B,H,S,64]
    ushort* vb   = kb + NX;           // V^T[B,H,64,S]
    ushort* yb   = vb + NX;           // attn out [B*S][DMODEL]  (footprint ends here: 48MB)

    const float qscale = 0.03125f * LOG2E;  // 1/sqrt(1024) * log2(e)

    cast_all_kernel<<<dim3(8192), dim3(256), 0, stream>>>(x, Wq, Wk, Wv, Wo, xb, wqkv, wob, qscale);

    gemm_bt<0, 128, 2><<<dim3(32, 24), dim3(256), 0, stream>>>(xb, wqkv, DMODEL, qb, kb, vb, nullptr);
    attn_kernel<<<dim3(32, 16), dim3(512), 0, stream>>>(qb, kb, vb, am, yb);
    gemm_bt<1, 64, 4><<<dim3(32, 16), dim3(256), 0, stream>>>(yb, wob, DMODEL, nullptr, nullptr, nullptr, out);
}

// Round 18
// 116.112 us; speedup vs baseline: 1.0136x; 1.0136x over previous
//
#include <hip/hip_runtime.h>
#include <stdint.h>

#define S_LEN 2048
#define NBATCH 2
#define DMODEL 1024
#define NHEAD 16
#define HDIM 64
#define MROWS (NBATCH * S_LEN)   // 4096
#define LOG2E 1.44269504f

typedef __bf16 bf16x8 __attribute__((ext_vector_type(8)));
typedef float f32x4 __attribute__((ext_vector_type(4)));
typedef float f32x16 __attribute__((ext_vector_type(16)));
typedef uint32_t u32x4 __attribute__((ext_vector_type(4)));

__device__ __forceinline__ f32x4 mfma_bf16(bf16x8 a, bf16x8 b, f32x4 c) {
    return __builtin_amdgcn_mfma_f32_16x16x32_bf16(a, b, c, 0, 0, 0);
}
__device__ __forceinline__ f32x16 mfma32(bf16x8 a, bf16x8 b, f32x16 c) {
    return __builtin_amdgcn_mfma_f32_32x32x16_bf16(a, b, c, 0, 0, 0);
}

__device__ __forceinline__ ushort f2bf(float f) {
    __bf16 h = (__bf16)f;
    return __builtin_bit_cast(ushort, h);
}

// pack two f32 -> one u32 of 2x bf16 (low = lo, high = hi). No builtin on gfx950 (m240).
__device__ __forceinline__ uint32_t cvtpk(float lo, float hi) {
    uint32_t r;
    asm("v_cvt_pk_bf16_f32 %0, %1, %2" : "=v"(r) : "v"(lo), "v"(hi));
    return r;
}
// swap: a' = {lanes<32: a, lanes>=32: b(from low half)}, b' = {lanes<32: a(from high half), >=32: b}
__device__ __forceinline__ void pl32swap(uint32_t& a, uint32_t& b) {
    auto r = __builtin_amdgcn_permlane32_swap(a, b, false, false);
    a = r[0];
    b = r[1];
}
// cross-half (lane ^ 32) max via permlane32_swap -- pure VALU, no ds_bpermute round-trip.
__device__ __forceinline__ float xhalf_max(float x) {
    uint32_t u = __builtin_bit_cast(uint32_t, x);
    auto r = __builtin_amdgcn_permlane32_swap(u, u, false, false);
    return fmaxf(__builtin_bit_cast(float, r[0]), __builtin_bit_cast(float, r[1]));
}
__device__ __forceinline__ float fexp2(float x) { return __builtin_amdgcn_exp2f(x); }

#define MAX3(a, b, c) fmaxf(fmaxf((a), (b)), (c))   // clang fuses to v_max3_f32 (T17)

#define GLOAD_LDS16(gp, lp)                                                             \
    __builtin_amdgcn_global_load_lds((const uint32_t __attribute__((address_space(1)))*)(gp), \
                                     (uint32_t __attribute__((address_space(3)))*)(lp), 16, 0, 0)

// ---------------- fused fp32 -> bf16 cast for all 5 inputs (1 launch) ----------------
// blocks [0,4096): x (1M float4). [4096,5120): Wq (*qscale). [5120,6144): Wk.
// [6144,7168): Wv. [7168,8192): Wo. All regions exact multiples of 256 threads.
// NOTE: workspace footprint stays within 48MB (R9 lesson); mask math stays f32-exact
// in the attn loop (R11 lesson); no register-hoists across attn MFMA blocks (R13 lesson:
// VGPR ceiling -> scratch spill, 634MB/dispatch).
__global__ void cast_all_kernel(const float* __restrict__ x,  const float* __restrict__ Wq,
                                const float* __restrict__ Wk, const float* __restrict__ Wv,
                                const float* __restrict__ Wo,
                                ushort* __restrict__ xb, ushort* __restrict__ wqkv,
                                ushort* __restrict__ wob, float qscale) {
    const int blk = blockIdx.x;
    const float* src;
    ushort* dst;
    float scale = 1.0f;
    int base;
    if (blk < 4096)      { src = x;  dst = xb;                         base = blk; }
    else if (blk < 5120) { src = Wq; dst = wqkv;                       base = blk - 4096; scale = qscale; }
    else if (blk < 6144) { src = Wk; dst = wqkv + DMODEL * DMODEL;     base = blk - 5120; }
    else if (blk < 7168) { src = Wv; dst = wqkv + 2 * DMODEL * DMODEL; base = blk - 6144; }
    else                 { src = Wo; dst = wob;                        base = blk - 7168; }
    const int i = base * blockDim.x + threadIdx.x;
    float4 v = reinterpret_cast<const float4*>(src)[i];
    ushort4 o;
    o.x = f2bf(v.x * scale);
    o.y = f2bf(v.y * scale);
    o.z = f2bf(v.z * scale);
    o.w = f2bf(v.w * scale);
    reinterpret_cast<ushort4*>(dst)[i] = o;
}

// ---------------- bf16 GEMM, C = A * B^T  (A[M,K], B[N,K]) ----------------
// Natural block mapping (bx fastest; swizzles regressed -- do not swizzle).
// BN=128/NSUB=2 for gemm<0> (32KB staging, 3 blocks/CU); BN=64/NSUB=4 for gemm<1>
// (48KB, 2 blocks/CU; R10+R15 wins). NSUB divides the vmcnt(0)+barrier drain events.
// gemm<0> (EPI==0): coalesced epilogue via LDS transpose over the dead staging buffer
// (R16 win, +4.2us): T[128][136] XOR-swizzled, 8x fully-coalesced 16B stores/thread.
// gemm<1> (EPI==1): direct f32 stores (R17 refuted the transpose there: f32 64B runs
// are already L2-absorbed; the extra barrier+LDS pass cost +1.3us).
template <int EPI, int BN, int NSUB>
__global__ __launch_bounds__(256, 2) void gemm_bt(
    const ushort* __restrict__ A, const ushort* __restrict__ Bw, const int K,
    ushort* __restrict__ dq, ushort* __restrict__ dk, ushort* __restrict__ dv,
    float* __restrict__ dout)
{
    constexpr int NF = BN / 32;                       // N-fragments per wave (4 or 2)
    constexpr int STAGE = NSUB * (128 + BN) * 32;     // staging ushorts
    constexpr int TP = 136;                           // padded transpose row (8-mult for 16B align)
    constexpr int SM_SZ = (EPI == 0 && STAGE < 128 * TP) ? 128 * TP : STAGE;
    __shared__ __align__(16) ushort SMEM[SM_SZ];

    const int tid  = threadIdx.x;
    const int lane = tid & 63;
    const int w    = tid >> 6;
    const int wr   = (w >> 1) * 64;
    const int wc   = (w & 1) * (16 * NF);
    const int g    = lane >> 4;
    const int lr   = lane & 15;
    const int bm   = blockIdx.x * 128;
    const int bn   = blockIdx.y * BN;

    const int srowA  = w * 32 + (lane >> 2);
    const int srowB  = w * (BN / 4) + (lane >> 2);
    const int schunk = (lane & 3) * 8;

    const ushort* gA = A  + (size_t)(bm + srowA) * K + schunk;
    const ushort* gB = Bw + (size_t)(bn + srowB) * K + schunk;

    f32x4 acc[4][NF];
#pragma unroll
    for (int mf = 0; mf < 4; ++mf)
#pragma unroll
        for (int nf = 0; nf < NF; ++nf)
            acc[mf][nf] = (f32x4){0.f, 0.f, 0.f, 0.f};

    for (int kt = 0; kt < K; kt += 32 * NSUB) {
#pragma unroll
        for (int s = 0; s < NSUB; ++s) {
            ushort* As = &SMEM[s * 128 * 32];
            ushort* Bs = &SMEM[NSUB * 128 * 32 + s * BN * 32];
            GLOAD_LDS16(gA + kt + 32 * s, As + (w * 32) * 32);
            GLOAD_LDS16(gA + (size_t)16 * K + kt + 32 * s, As + (w * 32 + 16) * 32);
            GLOAD_LDS16(gB + kt + 32 * s, Bs + (w * (BN / 4)) * 32);
            if constexpr (BN == 128)
                GLOAD_LDS16(gB + (size_t)16 * K + kt + 32 * s, Bs + (w * (BN / 4) + 16) * 32);
        }
        __syncthreads();

#pragma unroll
        for (int hk = 0; hk < NSUB; ++hk) {
            const ushort* As = &SMEM[hk * 128 * 32];
            const ushort* Bs = &SMEM[NSUB * 128 * 32 + hk * BN * 32];
            bf16x8 af[4], bfv[NF];
#pragma unroll
            for (int mf = 0; mf < 4; ++mf)
                af[mf] = *(const bf16x8*)&As[(wr + mf * 16 + lr) * 32 + g * 8];
#pragma unroll
            for (int nf = 0; nf < NF; ++nf)
                bfv[nf] = *(const bf16x8*)&Bs[(wc + nf * 16 + lr) * 32 + g * 8];
#pragma unroll
            for (int mf = 0; mf < 4; ++mf)
#pragma unroll
                for (int nf = 0; nf < NF; ++nf)
                    acc[mf][nf] = mfma_bf16(af[mf], bfv[nf], acc[mf][nf]);
        }
        __syncthreads();
    }

    if constexpr (EPI == 0) {
        // ---- coalesced epilogue: LDS transpose pass over the dead staging buffer ----
        const int mat = bn >> 10;   // block is mat-pure (128 | 1024)
        ushort* T = SMEM;           // logical T[r][c], addr = r*TP + (c ^ ((r&7)*8))
        if (mat < 2) {
            // Q/K: T[gm][gn] (output rows = gm, contiguous dd = gn)
#pragma unroll
            for (int mf = 0; mf < 4; ++mf)
#pragma unroll
                for (int nf = 0; nf < NF; ++nf)
#pragma unroll
                    for (int i = 0; i < 4; ++i) {
                        const int r = wr + mf * 16 + 4 * g + i;
                        const int c = wc + nf * 16 + lr;
                        T[r * TP + (c ^ ((r & 7) * 8))] = f2bf(acc[mf][nf][i]);
                    }
        } else {
            // V: T[gn][gm] (output rows = gn-derived vrow, contiguous ss = gm)
#pragma unroll
            for (int mf = 0; mf < 4; ++mf)
#pragma unroll
                for (int nf = 0; nf < NF; ++nf)
#pragma unroll
                    for (int i = 0; i < 4; ++i) {
                        const int r = wc + nf * 16 + lr;
                        const int c = wr + mf * 16 + 4 * g + i;
                        T[r * TP + (c ^ ((r & 7) * 8))] = f2bf(acc[mf][nf][i]);
                    }
        }
        __syncthreads();
        // readback: 2048 16B-chunks / 256 threads = 8 each, fully coalesced stores
#pragma unroll
        for (int cc = 0; cc < 8; ++cc) {
            const int ch = tid + cc * 256;
            const int r  = ch >> 4;            // row 0..127
            const int e0 = (ch & 15) * 8;      // element offset (8-aligned)
            const bf16x8 v = *(const bf16x8*)&T[r * TP + (e0 ^ ((r & 7) * 8))];
            if (mat < 2) {
                const int gm  = bm + r;
                const int bb  = gm >> 11;
                const int ss  = gm & 2047;
                const int gnp = bn + e0;
                const int hh  = (gnp & 1023) >> 6;
                const int dd0 = gnp & 63;
                ushort* dst = (mat == 0 ? dq : dk) +
                              ((size_t)(bb * NHEAD + hh) * S_LEN + ss) * HDIM + dd0;
                *(bf16x8*)dst = v;
            } else {
                const int rr  = (bn & 1023) + r;
                const int hh  = rr >> 6;
                const int dd  = rr & 63;
                const int gm0 = bm + e0;
                const int bb  = gm0 >> 11;
                const int ss0 = gm0 & 2047;
                ushort* dst = dv + ((size_t)(bb * NHEAD + hh) * HDIM + dd) * S_LEN + ss0;
                *(bf16x8*)dst = v;
            }
        }
    } else {
#pragma unroll
        for (int mf = 0; mf < 4; ++mf)
#pragma unroll
            for (int nf = 0; nf < NF; ++nf)
#pragma unroll
                for (int i = 0; i < 4; ++i) {
                    const int gm = bm + wr + mf * 16 + 4 * g + i;
                    const int gn = bn + wc + nf * 16 + lr;
                    dout[(size_t)gm * DMODEL + gn] = acc[mf][nf][i];
                }
    }
}

// ---------------- flash attention v10 (verified R5/R7/R10, FROZEN): KV-split + in-reg P + ones-MFMA l ----------------
// grid (B*H, S/128), 512 threads = 8 waves. Waves 0-3: kv [0,1024); waves 4-7: kv [1024,2048),
// same 4x32 q-rows; partials merged through LDS at the end. Wave supply 4096 (16 waves/CU --
// structural cap: every split variant either blows LDS or needs a >=64MB global merge).
// P in-register (cvtpk+permlane32_swap); l via ones-A MFMA on the idle matrix pipe;
// cross-half max via permlane; max3 tree; K/V double-buffered; 1 barrier/tile.
// DO NOT: hoist load-arrays across MFMA blocks (R13: scratch blowup), remove staging
// (R12: 2.15x), fold mask through bf16 (R11), per-ks interleave (R3), XCD-swizzle (R8).
__global__ __launch_bounds__(512, 4) void attn_kernel(
    const ushort* __restrict__ Qp,   // [B*H][S][64]  (pre-scaled by log2e/32)
    const ushort* __restrict__ Kp,   // [B*H][S][64]
    const ushort* __restrict__ Vp,   // [B*H][64][S]  (transposed)
    const float*  __restrict__ mask, // [B][S]
    ushort* __restrict__ Y)          // [B*S][DMODEL]
{
    __shared__ __align__(16) ushort Ks[2][2][64 * 64]; // [grp][buf][kv][hd] chunk-swizzled
    __shared__ __align__(16) ushort Vs[2][2][64 * 64]; // [grp][buf][d][kv]  chunk-swizzled

    const int tid  = threadIdx.x;
    const int lane = tid & 63;
    const int w    = tid >> 6;       // 0..7
    const int qsub = w & 3;          // q sub-block within the 128-row block
    const int grp  = w >> 2;         // kv half: 0 -> [0,S/2), 1 -> [S/2,S)
    const int q    = lane & 31;      // lane's q-col / row index in 32-row frags
    const int hsel = lane >> 5;      // half-wave
    const int l7   = lane & 7;
    const int bh   = blockIdx.x;     // head-major grid
    const int b    = bh >> 4;
    const int h    = bh & 15;
    const int q0   = blockIdx.y * 128 + qsub * 32;

    const ushort* Qh = Qp + (size_t)bh * S_LEN * HDIM;
    const ushort* Kh = Kp + (size_t)bh * S_LEN * HDIM;
    const ushort* Vh = Vp + (size_t)bh * HDIM * S_LEN;
    const float*  mb = mask + (size_t)b * S_LEN;

    // Q fragments (B-operand): lane holds q-row q0+q, k-slice ks: hd = ks*16 + hsel*8 + 0..7
    bf16x8 qf[4];
#pragma unroll
    for (int ks = 0; ks < 4; ++ks)
        qf[ks] = *(const bf16x8*)&Qh[(size_t)(q0 + q) * HDIM + ks * 16 + hsel * 8];

    // ones A-fragment for the l-row MFMA
    const __bf16 oneb = (__bf16)1.0f;
    const bf16x8 onesf = {oneb, oneb, oneb, oneb, oneb, oneb, oneb, oneb};

    // staging: wave stages rows [qsub*8, qsub*8+8) and [+32) of its group's K and V^T tile.
    // gload_lds dest linear; global source pre-swizzled chunk = c8 ^ (row&7) (rule 21)
    const int srow = qsub * 8 + (lane >> 3);
    const int swz  = ((lane & 7) ^ ((lane >> 3) & 7)) * 8;
    const ushort* gK = Kh + (size_t)srow * HDIM + swz;
    const ushort* gV = Vh + (size_t)srow * S_LEN + swz;
    const int lK0 = (qsub * 8) * 64, lK1 = (qsub * 8 + 32) * 64;

    f32x16 acc0 = {}, acc1 = {}, lacc = {};
    float mrun = -__builtin_inff();

    const int kvbase = grp * (S_LEN / 2);
    const int NT = (S_LEN / 2) / 64;

    // prologue: stage tile 0 into buf 0
    GLOAD_LDS16(gK + (size_t)kvbase * HDIM, &Ks[grp][0][lK0]);
    GLOAD_LDS16(gK + (size_t)(kvbase + 32) * HDIM, &Ks[grp][0][lK1]);
    GLOAD_LDS16(gV + kvbase, &Vs[grp][0][lK0]);
    GLOAD_LDS16(gV + (size_t)32 * S_LEN + kvbase, &Vs[grp][0][lK1]);
    __syncthreads();

    int buf = 0;
    for (int t = 0; t < NT; ++t) {
        const int kv0 = kvbase + t * 64;
        if (t + 1 < NT) {   // prefetch next tile into other buffer (latency hides under compute)
            GLOAD_LDS16(gK + (size_t)(kv0 + 64) * HDIM, &Ks[grp][buf ^ 1][lK0]);
            GLOAD_LDS16(gK + (size_t)(kv0 + 96) * HDIM, &Ks[grp][buf ^ 1][lK1]);
            GLOAD_LDS16(gV + (kv0 + 64), &Vs[grp][buf ^ 1][lK0]);
            GLOAD_LDS16(gV + (size_t)32 * S_LEN + (kv0 + 64), &Vs[grp][buf ^ 1][lK1]);
        }

        // ---- S^T = K * Q^T : lane owns q-col q; kv rows per verified C/D map ----
        f32x16 sv0 = {}, sv1 = {};
        __builtin_amdgcn_s_setprio(1);
#pragma unroll
        for (int ks = 0; ks < 4; ++ks) {
            const int c = ((ks * 2 + hsel) ^ l7) * 8;
            const bf16x8 kf0 = *(const bf16x8*)&Ks[grp][buf][q * 64 + c];
            const bf16x8 kf1 = *(const bf16x8*)&Ks[grp][buf][(32 + q) * 64 + c];
            sv0 = mfma32(kf0, qf[ks], sv0);
            sv1 = mfma32(kf1, qf[ks], sv1);
        }
        __builtin_amdgcn_s_setprio(0);

        // ---- mask add (log2 units) ----
        // lane reg r holds kv = (r&3) + 8*(r>>2) + 4*hsel (+32 for sv1)
#pragma unroll
        for (int rq = 0; rq < 4; ++rq) {
            const float4 m0 = *(const float4*)&mb[kv0 + rq * 8 + 4 * hsel];
            const float4 m1 = *(const float4*)&mb[kv0 + 32 + rq * 8 + 4 * hsel];
            sv0[4 * rq + 0] = fmaf(m0.x, LOG2E, sv0[4 * rq + 0]);
            sv0[4 * rq + 1] = fmaf(m0.y, LOG2E, sv0[4 * rq + 1]);
            sv0[4 * rq + 2] = fmaf(m0.z, LOG2E, sv0[4 * rq + 2]);
            sv0[4 * rq + 3] = fmaf(m0.w, LOG2E, sv0[4 * rq + 3]);
            sv1[4 * rq + 0] = fmaf(m1.x, LOG2E, sv1[4 * rq + 0]);
            sv1[4 * rq + 1] = fmaf(m1.y, LOG2E, sv1[4 * rq + 1]);
            sv1[4 * rq + 2] = fmaf(m1.z, LOG2E, sv1[4 * rq + 2]);
            sv1[4 * rq + 3] = fmaf(m1.w, LOG2E, sv1[4 * rq + 3]);
        }

        // ---- per-lane max: max3 tree (17 ops), then cross-half via permlane ----
        {
            const float a0 = MAX3(sv0[0], sv0[1], sv0[2]);
            const float a1 = MAX3(sv0[3], sv0[4], sv0[5]);
            const float a2 = MAX3(sv0[6], sv0[7], sv0[8]);
            const float a3 = MAX3(sv0[9], sv0[10], sv0[11]);
            const float a4 = MAX3(sv0[12], sv0[13], sv0[14]);
            const float b0 = MAX3(sv1[0], sv1[1], sv1[2]);
            const float b1 = MAX3(sv1[3], sv1[4], sv1[5]);
            const float b2 = MAX3(sv1[6], sv1[7], sv1[8]);
            const float b3 = MAX3(sv1[9], sv1[10], sv1[11]);
            const float b4 = MAX3(sv1[12], sv1[13], sv1[14]);
            const float c0 = MAX3(sv0[15], a0, a1);
            const float c1 = MAX3(a2, a3, a4);
            const float c2 = MAX3(sv1[15], b0, b1);
            const float c3 = MAX3(b2, b3, b4);
            float pm = fmaxf(fmaxf(c0, c1), fmaxf(c2, c3));
            pm = xhalf_max(pm);   // both halves of a q-col agree (permlane, no LDS)

            // ---- defer-max (T13, THR=8 log2 units) ----
            if (__ballot(pm > mrun + 8.0f) != 0ull) {
                const float mn  = fmaxf(mrun, pm);
                const float fac = fexp2(mrun - mn);
                mrun = mn;
#pragma unroll
                for (int r = 0; r < 16; ++r) {
                    acc0[r] *= fac; acc1[r] *= fac; lacc[r] *= fac;
                }
            }
        }

        // ---- P = exp2(S - m) (32 independent exps; l comes from the ones-MFMA) ----
#pragma unroll
        for (int r = 0; r < 16; ++r) {
            sv0[r] = fexp2(sv0[r] - mrun);
            sv1[r] = fexp2(sv1[r] - mrun);
        }

        // ---- P -> PV B-fragments fully in-register (T12): cvt_pk pairs + permlane32_swap ----
        uint32_t pw[16];
#pragma unroll
        for (int i = 0; i < 8; ++i) pw[i]     = cvtpk(sv0[2 * i], sv0[2 * i + 1]);
#pragma unroll
        for (int i = 0; i < 8; ++i) pw[8 + i] = cvtpk(sv1[2 * i], sv1[2 * i + 1]);
#pragma unroll
        for (int g = 0; g < 4; ++g) {
            pl32swap(pw[g * 4 + 0], pw[g * 4 + 2]);
            pl32swap(pw[g * 4 + 1], pw[g * 4 + 3]);
        }

        // ---- O^T += V^T * P ; l-row += ones * P (idle matrix pipe) ----
        __builtin_amdgcn_s_setprio(1);
#pragma unroll
        for (int ks = 0; ks < 4; ++ks) {
            const int c = ((ks * 2 + hsel) ^ l7) * 8;
            const u32x4 pu = {pw[ks * 4 + 0], pw[ks * 4 + 1], pw[ks * 4 + 2], pw[ks * 4 + 3]};
            const bf16x8 pb  = __builtin_bit_cast(bf16x8, pu);
            const bf16x8 vf0 = *(const bf16x8*)&Vs[grp][buf][q * 64 + c];
            const bf16x8 vf1 = *(const bf16x8*)&Vs[grp][buf][(32 + q) * 64 + c];
            acc0 = mfma32(vf0, pb, acc0);
            acc1 = mfma32(vf1, pb, acc1);
            lacc = mfma32(onesf, pb, lacc);
        }
        __builtin_amdgcn_s_setprio(0);

        __syncthreads();   // drains prefetch vmcnt + all LDS reads of buf
        buf ^= 1;
    }

    const float lrun = lacc[0];   // every row of lacc = sum_k P[k][q]; reg 0 valid for all lanes

    // ---- merge the two kv-half partials through LDS (overlaid on dead K/V buffers) ----
    // xch: [qsub][r(32)][lane(64)] f32 = 32KB over Ks; mlx: [qsub][2][lane] f32 over Vs.
    float* xch = reinterpret_cast<float*>(&Ks[0][0][0]);
    float* mlx = reinterpret_cast<float*>(&Vs[0][0][0]);
    if (grp == 1) {
#pragma unroll
        for (int r = 0; r < 16; ++r) {
            xch[(qsub * 32 + r) * 64 + lane]      = acc0[r];
            xch[(qsub * 32 + 16 + r) * 64 + lane] = acc1[r];
        }
        mlx[(qsub * 2 + 0) * 64 + lane] = mrun;
        mlx[(qsub * 2 + 1) * 64 + lane] = lrun;
    }
    __syncthreads();
    if (grp == 0) {
        const float m2 = mlx[(qsub * 2 + 0) * 64 + lane];
        const float l2 = mlx[(qsub * 2 + 1) * 64 + lane];
        const float mN = fmaxf(mrun, m2);
        const float f1 = fexp2(mrun - mN);
        const float f2 = fexp2(m2 - mN);
        const float inv = 1.0f / (lrun * f1 + l2 * f2);
        const float* src = &xch[(qsub * 32) * 64 + lane];

        // epilogue: O^T -> Y[b*S+q][h*64+d], d = (r&3)+8*(r>>2)+4*hsel (+32 acc1)
        ushort* Yr = Y + (size_t)(b * S_LEN + q0 + q) * DMODEL + h * HDIM;
#pragma unroll
        for (int rq = 0; rq < 4; ++rq) {
            ushort4 o0, o1;
            float v0[4], v1[4];
#pragma unroll
            for (int j = 0; j < 4; ++j) {
                v0[j] = (acc0[4 * rq + j] * f1 + src[(4 * rq + j) * 64] * f2) * inv;
                v1[j] = (acc1[4 * rq + j] * f1 + src[(16 + 4 * rq + j) * 64] * f2) * inv;
            }
            o0.x = f2bf(v0[0]); o0.y = f2bf(v0[1]); o0.z = f2bf(v0[2]); o0.w = f2bf(v0[3]);
            o1.x = f2bf(v1[0]); o1.y = f2bf(v1[1]); o1.z = f2bf(v1[2]); o1.w = f2bf(v1[3]);
            *(ushort4*)&Yr[rq * 8 + 4 * hsel]      = o0;
            *(ushort4*)&Yr[32 + rq * 8 + 4 * hsel] = o1;
        }
    }
}

// ---------------- launch ----------------
extern "C" void kernel_launch(void* const* d_in, const int* in_sizes, int n_in,
                              void* d_out, int out_size, void* d_ws, size_t ws_size,
                              hipStream_t stream)
{
    (void)in_sizes; (void)n_in; (void)out_size; (void)ws_size;
    const float* x  = (const float*)d_in[0];
    const float* am = (const float*)d_in[1];
    const float* Wq = (const float*)d_in[2];
    const float* Wk = (const float*)d_in[3];
    const float* Wv = (const float*)d_in[4];
    const float* Wo = (const float*)d_in[5];
    float* out = (float*)d_out;

    const size_t NX = (size_t)MROWS * DMODEL;   // 4M elems
    const size_t NW = (size_t)DMODEL * DMODEL;  // 1M elems

    ushort* xb   = (ushort*)d_ws;     // x bf16
    ushort* wqkv = xb + NX;           // stacked Wq|Wk|Wv bf16
    ushort* wob  = wqkv + 3 * NW;     // Wo bf16
    ushort* qb   = wob + NW;          // Q  [B,H,S,64] (pre-scaled by log2e/32)
    ushort* kb   = qb + NX;           // K  [B,H,S,64]
    ushort* vb   = kb + NX;           // V^T[B,H,64,S]
    ushort* yb   = vb + NX;           // attn out [B*S][DMODEL]  (footprint ends here: 48MB)

    const float qscale = 0.03125f * LOG2E;  // 1/sqrt(1024) * log2(e)

    cast_all_kernel<<<dim3(8192), dim3(256), 0, stream>>>(x, Wq, Wk, Wv, Wo, xb, wqkv, wob, qscale);

    gemm_bt<0, 128, 2><<<dim3(32, 24), dim3(256), 0, stream>>>(xb, wqkv, DMODEL, qb, kb, vb, nullptr);
    attn_kernel<<<dim3(32, 16), dim3(512), 0, stream>>>(qb, kb, vb, am, yb);
    gemm_bt<1, 64, 4><<<dim3(32, 16), dim3(256), 0, stream>>>(yb, wob, DMODEL, nullptr, nullptr, nullptr, out);
}